// Round 1
// baseline (1382.185 us; speedup 1.0000x reference)
//
#include <hip/hip_runtime.h>
#include <math.h>

#define NSMP 1024
#define NZ 10
#define NLENS 29
#define NPAIR 45
#define GPAIR 5
#define CPB 4
#define CSTR 1028

static __device__ __forceinline__ float2 cmulf(float2 a, float2 b){
    return make_float2(a.x*b.x - a.y*b.y, a.x*b.y + a.y*b.x);
}
#define SW(i) ((i) ^ (((i)>>5)&31))

static constexpr double PI2   = 6.283185307179586;
static constexpr double KD    = PI2/0.00051;           // 2*pi/lambda
static constexpr double F0D   = 1.0/(2.0*(3.6/1024.0)); // 1/(2*PS)
static constexpr double FSTEP = 2.0*F0D/1023.0;
static constexpr double IL2D  = (1.0/0.00051)*(1.0/0.00051);
static constexpr double TPPID = PI2*8.74;              // 2*pi*T_PROP

// ---- twiddle fill: W[t] = exp(-2*pi*i*t/1024) ----
static __device__ __forceinline__ void fill_W(float2* W, int tid, int nthr){
    for (int t = tid; t < 1024; t += nthr){
        float a = (float)((double)t * (-PI2/1024.0));
        float s, c; sincosf(a, &s, &c);
        W[t] = make_float2(c, s);
    }
}

// ---- in-LDS radix-4 Stockham FFT, 1024 points, in natural order in/out.
// buf: this FFT's 1024 complex slice (accessed via SW swizzle). TPF threads, tid in [0,TPF).
// Caller must have a __syncthreads() between populating buf and calling this.
template<bool INV, int TPF>
static __device__ void fft1024_lds(float2* buf, const float2* W, int tid){
    const int WPT = 256/TPF;
    int Ns = 1;
    #pragma unroll
    for (int stage = 0; stage < 5; ++stage){
        float2 v[WPT][4];
        #pragma unroll
        for (int w = 0; w < WPT; ++w){
            int j = tid + w*TPF;
            float2 a0 = buf[SW(j)];
            float2 a1 = buf[SW(j+256)];
            float2 a2 = buf[SW(j+512)];
            float2 a3 = buf[SW(j+768)];
            int m  = j & (Ns-1);
            int tb = m * (256/Ns);
            float2 w1 = W[tb], w2 = W[2*tb], w3 = W[3*tb];
            if (INV){ w1.y = -w1.y; w2.y = -w2.y; w3.y = -w3.y; }
            a1 = cmulf(a1, w1); a2 = cmulf(a2, w2); a3 = cmulf(a3, w3);
            float2 t0 = make_float2(a0.x+a2.x, a0.y+a2.y);
            float2 t1 = make_float2(a0.x-a2.x, a0.y-a2.y);
            float2 t2 = make_float2(a1.x+a3.x, a1.y+a3.y);
            float2 t3 = make_float2(a1.x-a3.x, a1.y-a3.y);
            float2 x0 = make_float2(t0.x+t2.x, t0.y+t2.y);
            float2 x2 = make_float2(t0.x-t2.x, t0.y-t2.y);
            float2 x1, x3;
            if (!INV){ // X1 = t1 - i*t3 ; X3 = t1 + i*t3
                x1 = make_float2(t1.x + t3.y, t1.y - t3.x);
                x3 = make_float2(t1.x - t3.y, t1.y + t3.x);
            } else {
                x1 = make_float2(t1.x - t3.y, t1.y + t3.x);
                x3 = make_float2(t1.x + t3.y, t1.y - t3.x);
            }
            v[w][0]=x0; v[w][1]=x1; v[w][2]=x2; v[w][3]=x3;
        }
        __syncthreads();
        #pragma unroll
        for (int w = 0; w < WPT; ++w){
            int j = tid + w*TPF;
            int m = j & (Ns-1);
            int idxD = ((j - m) << 2) + m;     // (j/Ns)*4Ns + m
            buf[SW(idxD)]      = v[w][0];
            buf[SW(idxD+Ns)]   = v[w][1];
            buf[SW(idxD+2*Ns)] = v[w][2];
            buf[SW(idxD+3*Ns)] = v[w][3];
        }
        __syncthreads();
        Ns <<= 2;
    }
}

// reduce phase mod 2pi in double, then accurate float sincos → (cos, sin)
static __device__ __forceinline__ float2 expi_from_double(double ph){
    double t = ph * (1.0/PI2);
    t -= floor(t);
    float th = (float)(t * PI2);
    float s, c; sincosf(th, &s, &c);
    return make_float2(c, s);
}

// ---- K0: lens surface phase + aperture ----
__global__ __launch_bounds__(256) void k_lens(const float* __restrict__ rlist,
        const float* __restrict__ xpos, const float* __restrict__ ypos,
        float2* __restrict__ phiA){
    int idx = blockIdx.x*256 + threadIdx.x;
    int r = idx >> 10, c = idx & 1023;
    float x = (float)(-1.8 + c*(3.6/1023.0));
    float y = (float)(-1.8 + r*(3.6/1023.0));
    const float ca2  = (float)(0.165*0.165);
    float T = 0.f; int any = 0;
    for (int l = 0; l < NLENS; ++l){
        float dx = x - xpos[l], dy = y - ypos[l];
        float d2 = dx*dx + dy*dy;
        if (d2 <= ca2){
            float rr = rlist[l];
            T += rr - sqrtf(fmaxf(rr*rr - d2, 1e-12f));
            any = 1;
        }
    }
    float ap = (any && (x*x + y*y) <= 0.81f) ? 1.f : 0.f;
    float phi = (float)(KD*(1.515 - 1.0)) * T;
    phiA[idx] = make_float2(phi, ap);
}

// ---- P1 (row): generate U1, forward row FFT ----
__global__ __launch_bounds__(256) void k_p1(const float2* __restrict__ phiA,
        const float* __restrict__ defocus, float2* __restrict__ S){
    __shared__ float2 buf[1024];
    __shared__ float2 W[1024];
    int row = blockIdx.x, z = blockIdx.y, tid = threadIdx.x;
    fill_W(W, tid, 256);
    float zf = defocus[z];
    float y  = (float)(-1.8 + row*(3.6/1023.0));
    const float KF = (float)KD;
    const float2* pha = phiA + ((size_t)row << 10);
    for (int k = 0; k < 4; ++k){
        int c = tid + k*256;
        float x = (float)(-1.8 + c*(3.6/1023.0));
        float2 pa = pha[c];
        float2 u  = make_float2(0.f, 0.f);
        if (pa.y != 0.f){
            float q      = x*x + y*y;
            float phi_in = (KF*q) / (2.0f*zf);
            float phs    = phi_in + pa.x;
            u = expi_from_double((double)phs);
        }
        buf[SW(c)] = u;
    }
    __syncthreads();
    fft1024_lds<false,256>(buf, W, tid);
    float2* Srow = S + ((size_t)z << 20) + ((size_t)row << 10);
    for (int k = 0; k < 4; ++k){
        int c = tid + k*256;
        Srow[c] = buf[SW(c)];
    }
}

// ---- P2 (col): forward col FFT, *H, inverse col FFT (in place) ----
__global__ __launch_bounds__(256) void k_p2(float2* __restrict__ S){
    __shared__ float2 buf[CPB*CSTR];
    __shared__ float2 W[1024];
    int tid = threadIdx.x, cb = blockIdx.x, z = blockIdx.y;
    int c0 = cb*CPB;
    fill_W(W, tid, 256);
    float2* Sz = S + ((size_t)z << 20);
    for (int it = 0; it < 16; ++it){
        int rr = it*64 + (tid>>2), cc = tid & 3;
        buf[cc*CSTR + SW(rr)] = Sz[((size_t)rr << 10) + c0 + cc];
    }
    __syncthreads();
    int col = tid >> 6, ft = tid & 63;
    fft1024_lds<false,64>(buf + col*CSTR, W, ft);
    // multiply by H (ifftshifted transfer function), computed from indices
    const float il2f = (float)IL2D;
    const float pf   = (float)TPPID;
    int cglob = c0 + col;
    int cs = (cglob + 512) & 1023;
    float fc = (float)(-F0D + cs*FSTEP);
    float fc2 = __fmul_rn(fc, fc);
    for (int w = 0; w < 16; ++w){
        int i  = ft + w*64;
        int rs = (i + 512) & 1023;
        float fr  = (float)(-F0D + rs*FSTEP);
        float kz2 = __fsub_rn(__fsub_rn(il2f, fc2), __fmul_rn(fr, fr));
        float kzf = sqrtf(fmaxf(kz2, 0.f));
        float phf = __fmul_rn(pf, kzf);
        float2 h  = expi_from_double((double)phf);
        int a = col*CSTR + SW(i);
        buf[a] = cmulf(buf[a], h);
    }
    __syncthreads();
    fft1024_lds<true,64>(buf + col*CSTR, W, ft);
    const float sc = 1.0f/1024.0f;
    for (int it = 0; it < 16; ++it){
        int rr = it*64 + (tid>>2), cc = tid & 3;
        float2 v = buf[cc*CSTR + SW(rr)];
        Sz[((size_t)rr << 10) + c0 + cc] = make_float2(v.x*sc, v.y*sc);
    }
}

// ---- P3 (row): inverse row FFT -> p=|u|^2, partial sum(p), forward row FFT of p ----
__global__ __launch_bounds__(256) void k_p3(float2* __restrict__ S, float* __restrict__ sumPart){
    __shared__ float2 buf[1024];
    __shared__ float2 W[1024];
    __shared__ float red[4];
    int row = blockIdx.x, z = blockIdx.y, tid = threadIdx.x;
    fill_W(W, tid, 256);
    float2* Srow = S + ((size_t)z << 20) + ((size_t)row << 10);
    for (int k = 0; k < 4; ++k){ int c = tid + k*256; buf[SW(c)] = Srow[c]; }
    __syncthreads();
    fft1024_lds<true,256>(buf, W, tid);
    const float s2 = (1.0f/1024.0f)*(1.0f/1024.0f);
    float pv[4]; float lsum = 0.f;
    for (int k = 0; k < 4; ++k){
        int c = tid + k*256;
        float2 u = buf[SW(c)];
        float p  = (u.x*u.x + u.y*u.y) * s2;
        pv[k] = p; lsum += p;
    }
    // own-slot rewrite (same addresses this thread read) — no barrier needed yet
    for (int k = 0; k < 4; ++k){ int c = tid + k*256; buf[SW(c)] = make_float2(pv[k], 0.f); }
    for (int o = 32; o > 0; o >>= 1) lsum += __shfl_down(lsum, o, 64);
    if ((tid & 63) == 0) red[tid >> 6] = lsum;
    __syncthreads();   // covers both buf p-writes and red
    if (tid == 0) sumPart[z*1024 + row] = red[0]+red[1]+red[2]+red[3];
    fft1024_lds<false,256>(buf, W, tid);
    for (int k = 0; k < 4; ++k){ int c = tid + k*256; Srow[c] = buf[SW(c)]; }
}

// ---- R1: reduce sum(p) partials (double) ----
__global__ __launch_bounds__(256) void k_r1(const float* __restrict__ sumPart, double* __restrict__ sums){
    __shared__ double dred[4];
    int z = blockIdx.x, tid = threadIdx.x;
    double s = 0.0;
    for (int i = tid; i < 1024; i += 256) s += (double)sumPart[z*1024 + i];
    for (int o = 32; o > 0; o >>= 1) s += __shfl_down(s, o, 64);
    if ((tid & 63) == 0) dred[tid >> 6] = s;
    __syncthreads();
    if (tid == 0) sums[z] = dred[0]+dred[1]+dred[2]+dred[3];
}

// ---- P4 (col): forward col FFT, scale by 1/sum -> S; masked diag partials ----
__global__ __launch_bounds__(256) void k_p4(float2* __restrict__ S, const double* __restrict__ sums,
        const float* __restrict__ tF, const float* __restrict__ dmask, float* __restrict__ dpart){
    __shared__ float2 buf[CPB*CSTR];
    __shared__ float2 W[1024];
    __shared__ float red[4];
    int tid = threadIdx.x, cb = blockIdx.x, z = blockIdx.y;
    int c0 = cb*CPB;
    fill_W(W, tid, 256);
    float2* Sz = S + ((size_t)z << 20);
    for (int it = 0; it < 16; ++it){
        int rr = it*64 + (tid>>2), cc = tid & 3;
        buf[cc*CSTR + SW(rr)] = Sz[((size_t)rr << 10) + c0 + cc];
    }
    __syncthreads();
    int col = tid >> 6, ft = tid & 63;
    fft1024_lds<false,64>(buf + col*CSTR, W, ft);
    float inv = (float)(1.0/sums[z]);
    const float nrm = 1.0f/1048576.0f;
    float dacc = 0.f;
    for (int w = 0; w < 16; ++w){
        int i = ft + w*64;
        int a = col*CSTR + SW(i);
        float2 s = buf[a]; s.x *= inv; s.y *= inv; buf[a] = s;
        size_t el = ((size_t)i << 10) + c0 + col;
        float d = (s.x*s.x + s.y*s.y - tF[el]) * nrm;
        dacc += dmask[el] * d * d;
    }
    __syncthreads();
    for (int it = 0; it < 16; ++it){
        int rr = it*64 + (tid>>2), cc = tid & 3;
        Sz[((size_t)rr << 10) + c0 + cc] = buf[cc*CSTR + SW(rr)];
    }
    for (int o = 32; o > 0; o >>= 1) dacc += __shfl_down(dacc, o, 64);
    if ((tid & 63) == 0) red[tid >> 6] = dacc;
    __syncthreads();
    if (tid == 0) dpart[z*256 + cb] = red[0]+red[1]+red[2]+red[3];
}

static __device__ __forceinline__ void pair_of(int p, int& a, int& b){
    int i = 0, c = NZ-1;
    while (p >= c){ p -= c; ++i; --c; }
    a = i; b = i + 1 + p;
}

// ---- pairA (col): Fcorr = conj(Si)*Sj, inverse col FFT -> U ----
__global__ __launch_bounds__(256) void k_pairA(const float2* __restrict__ S,
        float2* __restrict__ U, int pbase){
    __shared__ float2 buf[CPB*CSTR];
    __shared__ float2 W[1024];
    int tid = threadIdx.x, cb = blockIdx.x, pg = blockIdx.y;
    int i1, i2; pair_of(pbase + pg, i1, i2);
    const float2* Sa = S + ((size_t)i1 << 20);
    const float2* Sb = S + ((size_t)i2 << 20);
    int c0 = cb*CPB;
    fill_W(W, tid, 256);
    for (int it = 0; it < 16; ++it){
        int rr = it*64 + (tid>>2), cc = tid & 3;
        size_t el = ((size_t)rr << 10) + c0 + cc;
        float2 a = Sa[el], b = Sb[el];
        buf[cc*CSTR + SW(rr)] = make_float2(a.x*b.x + a.y*b.y, a.x*b.y - a.y*b.x);
    }
    __syncthreads();
    int col = tid >> 6, ft = tid & 63;
    fft1024_lds<true,64>(buf + col*CSTR, W, ft);
    const float sc = 1.0f/1024.0f;
    float2* Up = U + ((size_t)pg << 20);
    for (int it = 0; it < 16; ++it){
        int rr = it*64 + (tid>>2), cc = tid & 3;
        float2 v = buf[cc*CSTR + SW(rr)];
        Up[((size_t)rr << 10) + c0 + cc] = make_float2(v.x*sc, v.y*sc);
    }
}

// ---- pairB (row): inverse row FFT, c=|u|/N, per-row (max, sum exp) partials ----
__global__ __launch_bounds__(256) void k_pairB(const float2* __restrict__ U,
        float2* __restrict__ lsePart, int pbase){
    __shared__ float2 buf[1024];
    __shared__ float2 W[1024];
    __shared__ float red[8];
    int row = blockIdx.x, pg = blockIdx.y, tid = threadIdx.x;
    fill_W(W, tid, 256);
    const float2* Urow = U + ((size_t)pg << 20) + ((size_t)row << 10);
    for (int k = 0; k < 4; ++k){ int c = tid + k*256; buf[SW(c)] = Urow[c]; }
    __syncthreads();
    fft1024_lds<true,256>(buf, W, tid);
    const float sc = 1.0f/1024.0f;
    float cv[4]; float lmax = -1.f;
    for (int k = 0; k < 4; ++k){
        int c = tid + k*256;
        float2 u = buf[SW(c)];
        float m = sqrtf(u.x*u.x + u.y*u.y) * sc;
        cv[k] = m; lmax = fmaxf(lmax, m);
    }
    for (int o = 32; o > 0; o >>= 1) lmax = fmaxf(lmax, __shfl_down(lmax, o, 64));
    if ((tid & 63) == 0) red[tid >> 6] = lmax;
    __syncthreads();
    float M = fmaxf(fmaxf(red[0], red[1]), fmaxf(red[2], red[3]));
    float ls = 0.f;
    for (int k = 0; k < 4; ++k) ls += expf((cv[k] - M) * 100.0f);
    for (int o = 32; o > 0; o >>= 1) ls += __shfl_down(ls, o, 64);
    if ((tid & 63) == 0) red[4 + (tid >> 6)] = ls;
    __syncthreads();
    if (tid == 0)
        lsePart[(size_t)(pbase + pg)*1024 + row] =
            make_float2(M, red[4]+red[5]+red[6]+red[7]);
}

// ---- final: 10 diag sums + 45 off (global logsumexp combine) ----
__global__ __launch_bounds__(256) void k_final(const float* __restrict__ dpart,
        const float2* __restrict__ lsePart, float* __restrict__ out){
    __shared__ double dred[4];
    __shared__ float fred[4];
    int b = blockIdx.x, tid = threadIdx.x;
    if (b < NZ){
        double s = (double)dpart[b*256 + tid];
        for (int o = 32; o > 0; o >>= 1) s += __shfl_down(s, o, 64);
        if ((tid & 63) == 0) dred[tid >> 6] = s;
        __syncthreads();
        if (tid == 0) out[b] = (float)(dred[0]+dred[1]+dred[2]+dred[3]);
    } else {
        int p = b - NZ;
        const float2* lp = lsePart + (size_t)p*1024;
        float2 v[4]; float m = -1e30f;
        for (int k = 0; k < 4; ++k){ v[k] = lp[tid + k*256]; m = fmaxf(m, v[k].x); }
        for (int o = 32; o > 0; o >>= 1) m = fmaxf(m, __shfl_down(m, o, 64));
        if ((tid & 63) == 0) fred[tid >> 6] = m;
        __syncthreads();
        float M = fmaxf(fmaxf(fred[0], fred[1]), fmaxf(fred[2], fred[3]));
        double s = 0.0;
        for (int k = 0; k < 4; ++k) s += (double)v[k].y * (double)expf((v[k].x - M)*100.0f);
        for (int o = 32; o > 0; o >>= 1) s += __shfl_down(s, o, 64);
        if ((tid & 63) == 0) dred[tid >> 6] = s;
        __syncthreads();
        if (tid == 0)
            out[NZ + p] = (float)(30.0*(double)M + 0.3*log(dred[0]+dred[1]+dred[2]+dred[3]));
    }
}

extern "C" void kernel_launch(void* const* d_in, const int* in_sizes, int n_in,
                              void* d_out, int out_size, void* d_ws, size_t ws_size,
                              hipStream_t stream){
    const float* rlist   = (const float*)d_in[0];
    const float* xpos    = (const float*)d_in[1];
    const float* ypos    = (const float*)d_in[2];
    const float* defocus = (const float*)d_in[3];
    const float* tF      = (const float*)d_in[4];
    const float* dmask   = (const float*)d_in[5];
    float* out = (float*)d_out;

    char* ws = (char*)d_ws;
    float2* S       = (float2*)(ws);                       // NZ * 1024^2 * 8 = 80 MiB
    float2* U       = (float2*)(ws + 83886080);            // GPAIR * 8 MiB = 40 MiB
    float2* phiA    = (float2*)(ws + 125829120);           // 8 MiB
    float*  sumPart = (float*) (ws + 134217728);           // NZ*1024*4
    double* sums    = (double*)(ws + 134217728 + 65536);   // NZ*8
    float*  dpart   = (float*) (ws + 134217728 + 66560);   // NZ*256*4
    float2* lsePart = (float2*)(ws + 134217728 + 82944);   // 45*1024*8

    k_lens<<<4096, 256, 0, stream>>>(rlist, xpos, ypos, phiA);
    k_p1 <<<dim3(1024, NZ), 256, 0, stream>>>(phiA, defocus, S);
    k_p2 <<<dim3(256,  NZ), 256, 0, stream>>>(S);
    k_p3 <<<dim3(1024, NZ), 256, 0, stream>>>(S, sumPart);
    k_r1 <<<NZ, 256, 0, stream>>>(sumPart, sums);
    k_p4 <<<dim3(256,  NZ), 256, 0, stream>>>(S, sums, tF, dmask, dpart);
    for (int g = 0; g < NPAIR/GPAIR; ++g){
        k_pairA<<<dim3(256,  GPAIR), 256, 0, stream>>>(S, U, g*GPAIR);
        k_pairB<<<dim3(1024, GPAIR), 256, 0, stream>>>(U, lsePart, g*GPAIR);
    }
    k_final<<<NZ + NPAIR, 256, 0, stream>>>(dpart, lsePart, out);
}

// Round 2
// 503.952 us; speedup vs baseline: 2.7427x; 2.7427x over previous
//
#include <hip/hip_runtime.h>
#include <math.h>

#define NSMP 1024
#define NZ 10
#define NLENS 29
#define NPAIR 45
#define NUNIT 23
#define UBATCH 4
#define CPB 4
#define CSTR 1028

static __device__ __forceinline__ float2 cmulf(float2 a, float2 b){
    return make_float2(a.x*b.x - a.y*b.y, a.x*b.y + a.y*b.x);
}
#define SW(i) ((i) ^ (((i)>>5)&31))

static constexpr double PI2   = 6.283185307179586;
static constexpr double KD    = PI2/0.00051;            // 2*pi/lambda
static constexpr double F0D   = 1.0/(2.0*(3.6/1024.0)); // 1/(2*PS)
static constexpr double FSTEP = 2.0*F0D/1023.0;
static constexpr double IL2D  = (1.0/0.00051)*(1.0/0.00051);
static constexpr double TPPID = PI2*8.74;               // 2*pi*T_PROP

// ---- twiddle fill (swizzled storage): W[SW(t)] = exp(-2*pi*i*t/1024) ----
static __device__ __forceinline__ void fill_W(float2* W, int tid, int nthr){
    for (int t = tid; t < 1024; t += nthr){
        float a = (float)((double)t * (-PI2/1024.0));
        float s, c; sincosf(a, &s, &c);
        W[SW(t)] = make_float2(c, s);
    }
}

// radix-4 butterfly, twiddles w1..w3 applied to a1..a3 (forward); INV conjugates.
template<bool INV>
static __device__ __forceinline__ void bf4(const float2 a[4], float2 w1, float2 w2, float2 w3, float2 o[4]){
    if (INV){ w1.y = -w1.y; w2.y = -w2.y; w3.y = -w3.y; }
    float2 a1 = cmulf(a[1], w1), a2 = cmulf(a[2], w2), a3 = cmulf(a[3], w3);
    float2 t0 = make_float2(a[0].x+a2.x, a[0].y+a2.y);
    float2 t1 = make_float2(a[0].x-a2.x, a[0].y-a2.y);
    float2 t2 = make_float2(a1.x+a3.x, a1.y+a3.y);
    float2 t3 = make_float2(a1.x-a3.x, a1.y-a3.y);
    o[0] = make_float2(t0.x+t2.x, t0.y+t2.y);
    o[2] = make_float2(t0.x-t2.x, t0.y-t2.y);
    if (!INV){
        o[1] = make_float2(t1.x + t3.y, t1.y - t3.x);
        o[3] = make_float2(t1.x - t3.y, t1.y + t3.x);
    } else {
        o[1] = make_float2(t1.x - t3.y, t1.y + t3.x);
        o[3] = make_float2(t1.x + t3.y, t1.y - t3.x);
    }
}
template<bool INV>
static __device__ __forceinline__ void bf4nt(const float2 a[4], float2 o[4]){
    float2 t0 = make_float2(a[0].x+a[2].x, a[0].y+a[2].y);
    float2 t1 = make_float2(a[0].x-a[2].x, a[0].y-a[2].y);
    float2 t2 = make_float2(a[1].x+a[3].x, a[1].y+a[3].y);
    float2 t3 = make_float2(a[1].x-a[3].x, a[1].y-a[3].y);
    o[0] = make_float2(t0.x+t2.x, t0.y+t2.y);
    o[2] = make_float2(t0.x-t2.x, t0.y-t2.y);
    if (!INV){
        o[1] = make_float2(t1.x + t3.y, t1.y - t3.x);
        o[3] = make_float2(t1.x - t3.y, t1.y + t3.x);
    } else {
        o[1] = make_float2(t1.x - t3.y, t1.y + t3.x);
        o[3] = make_float2(t1.x + t3.y, t1.y - t3.x);
    }
}

// ===== radix-16 (two fused radix-4 stages) 1024-pt Stockham, 64 threads/FFT =====
// Every pass loads the same pattern: a[k][q] = B[SW(t + 64k + 256q)]
static __device__ __forceinline__ void r16_load(const float2* B, int t, float2 a[4][4]){
    #pragma unroll
    for (int k = 0; k < 4; ++k)
        #pragma unroll
        for (int q = 0; q < 4; ++q)
            a[k][q] = B[SW(t + 64*k + 256*q)];
}
// pass 1: stages Ns=1 and Ns=4. out z[i][d] -> position 16t + i + 4d
template<bool INV>
static __device__ __forceinline__ void r16_s14(const float2 a[4][4], const float2* W, float2 z[4][4]){
    float2 y[4][4];
    #pragma unroll
    for (int k = 0; k < 4; ++k) bf4nt<INV>(a[k], y[k]);
    #pragma unroll
    for (int i = 0; i < 4; ++i){
        float2 b[4] = { y[0][i], y[1][i], y[2][i], y[3][i] };
        bf4<INV>(b, W[SW(64*i)], W[SW(128*i)], W[SW(192*i)], z[i]);
    }
}
static __device__ __forceinline__ void r16_st1(float2* B, int t, const float2 z[4][4]){
    #pragma unroll
    for (int i = 0; i < 4; ++i)
        #pragma unroll
        for (int d = 0; d < 4; ++d)
            B[SW(16*t + i + 4*d)] = z[i][d];
}
// pass 2: stages Ns=16 and Ns=64. out z[n][d] -> position 256*(t>>4) + (t&15) + 16n + 64d
template<bool INV>
static __device__ __forceinline__ void r16_s16_64(const float2 a[4][4], const float2* W, int t, float2 z[4][4]){
    int mt = t & 15;
    float2 y[4][4];
    float2 w1 = W[SW(16*mt)], w2 = W[SW(32*mt)], w3 = W[SW(48*mt)];
    #pragma unroll
    for (int k = 0; k < 4; ++k) bf4<INV>(a[k], w1, w2, w3, y[k]);
    #pragma unroll
    for (int n = 0; n < 4; ++n){
        int m2 = mt + 16*n;
        float2 b[4] = { y[0][n], y[1][n], y[2][n], y[3][n] };
        bf4<INV>(b, W[SW(4*m2)], W[SW(8*m2)], W[SW(12*m2)], z[n]);
    }
}
static __device__ __forceinline__ void r16_st2(float2* B, int t, const float2 z[4][4]){
    int base = 256*(t>>4) + (t&15);
    #pragma unroll
    for (int n = 0; n < 4; ++n)
        #pragma unroll
        for (int d = 0; d < 4; ++d)
            B[SW(base + 16*n + 64*d)] = z[n][d];
}
// pass 3: stage Ns=256. out z[k][d] = element (t + 64k + 256d), natural order.
template<bool INV>
static __device__ __forceinline__ void r16_s256(const float2 a[4][4], const float2* W, int t, float2 z[4][4]){
    #pragma unroll
    for (int k = 0; k < 4; ++k){
        int j = t + 64*k;
        bf4<INV>(a[k], W[SW(j)], W[SW(2*j)], W[SW(3*j)], z[k]);
    }
}
static __device__ __forceinline__ void r16_st3(float2* B, int t, const float2 z[4][4]){
    #pragma unroll
    for (int k = 0; k < 4; ++k)
        #pragma unroll
        for (int d = 0; d < 4; ++d)
            B[SW(t + 64*k + 256*d)] = z[k][d];
}
// full FFT, result left in z (element t + 64k + 256d), NOT stored to LDS
template<bool INV>
static __device__ void r16_fft(float2* B, const float2* W, int t, float2 z[4][4]){
    float2 a[4][4];
    r16_load(B, t, a); r16_s14<INV>(a, W, z);
    __syncthreads(); r16_st1(B, t, z); __syncthreads();
    r16_load(B, t, a); r16_s16_64<INV>(a, W, t, z);
    __syncthreads(); r16_st2(B, t, z); __syncthreads();
    r16_load(B, t, a); r16_s256<INV>(a, W, t, z);
}

// ===== radix-4 Stockham, 256 threads/FFT (row kernels) =====
template<bool INV, int TPF>
static __device__ void fft1024_lds(float2* buf, const float2* W, int tid){
    const int WPT = 256/TPF;
    int Ns = 1;
    #pragma unroll
    for (int stage = 0; stage < 5; ++stage){
        float2 v[WPT][4];
        #pragma unroll
        for (int w = 0; w < WPT; ++w){
            int j = tid + w*TPF;
            float2 a[4] = { buf[SW(j)], buf[SW(j+256)], buf[SW(j+512)], buf[SW(j+768)] };
            int m  = j & (Ns-1);
            int tb = m * (256/Ns);
            bf4<INV>(a, W[SW(tb)], W[SW(2*tb)], W[SW(3*tb)], v[w]);
        }
        __syncthreads();
        #pragma unroll
        for (int w = 0; w < WPT; ++w){
            int j = tid + w*TPF;
            int m = j & (Ns-1);
            int idxD = ((j - m) << 2) + m;
            buf[SW(idxD)]      = v[w][0];
            buf[SW(idxD+Ns)]   = v[w][1];
            buf[SW(idxD+2*Ns)] = v[w][2];
            buf[SW(idxD+3*Ns)] = v[w][3];
        }
        __syncthreads();
        Ns <<= 2;
    }
}

static __device__ __forceinline__ float2 expi_from_double(double ph){
    double t = ph * (1.0/PI2);
    t -= floor(t);
    float th = (float)(t * PI2);
    float s, c; sincosf(th, &s, &c);
    return make_float2(c, s);
}

// ---- K0: lens surface phase + aperture ----
__global__ __launch_bounds__(256) void k_lens(const float* __restrict__ rlist,
        const float* __restrict__ xpos, const float* __restrict__ ypos,
        float2* __restrict__ phiA){
    int idx = blockIdx.x*256 + threadIdx.x;
    int r = idx >> 10, c = idx & 1023;
    float x = (float)(-1.8 + c*(3.6/1023.0));
    float y = (float)(-1.8 + r*(3.6/1023.0));
    const float ca2 = (float)(0.165*0.165);
    float T = 0.f; int any = 0;
    for (int l = 0; l < NLENS; ++l){
        float dx = x - xpos[l], dy = y - ypos[l];
        float d2 = dx*dx + dy*dy;
        if (d2 <= ca2){
            float rr = rlist[l];
            T += rr - sqrtf(fmaxf(rr*rr - d2, 1e-12f));
            any = 1;
        }
    }
    float ap = (any && (x*x + y*y) <= 0.81f) ? 1.f : 0.f;
    float phi = (float)(KD*(1.515 - 1.0)) * T;
    phiA[idx] = make_float2(phi, ap);
}

// ---- prep: HT[c*1024+r] = H(ifftshifted) value at (row=r, col=c) ----
__global__ __launch_bounds__(256) void k_prep_h(float2* __restrict__ HT){
    int idx = blockIdx.x*256 + threadIdx.x;
    int c = idx >> 10, r = idx & 1023;
    int cs = (c + 512) & 1023, rs = (r + 512) & 1023;
    float fc = (float)(-F0D + cs*FSTEP);
    float fr = (float)(-F0D + rs*FSTEP);
    float kz2 = __fsub_rn(__fsub_rn((float)IL2D, __fmul_rn(fc,fc)), __fmul_rn(fr,fr));
    float kzf = sqrtf(fmaxf(kz2, 0.f));
    float phf = __fmul_rn((float)TPPID, kzf);
    HT[idx] = expi_from_double((double)phf);
}

// ---- prep: TM[c*1024+r] = (tF[r][c], dmask[r][c]) (tiled transpose) ----
__global__ void k_prep_tm(const float* __restrict__ tF, const float* __restrict__ dm,
                          float2* __restrict__ TM){
    __shared__ float2 T[32][33];
    int bx = blockIdx.x, by = blockIdx.y;
    int tx = threadIdx.x, ty = threadIdx.y;
    #pragma unroll
    for (int j = 0; j < 4; ++j){
        int r = by*32 + ty + 8*j, c = bx*32 + tx;
        T[ty+8*j][tx] = make_float2(tF[(size_t)r*1024 + c], dm[(size_t)r*1024 + c]);
    }
    __syncthreads();
    #pragma unroll
    for (int j = 0; j < 4; ++j){
        int c = bx*32 + ty + 8*j, r = by*32 + tx;
        TM[(size_t)c*1024 + r] = T[tx][ty+8*j];
    }
}

// ---- P1 (row): generate U1, forward row FFT ----
__global__ __launch_bounds__(256) void k_p1(const float2* __restrict__ phiA,
        const float* __restrict__ defocus, float2* __restrict__ S){
    __shared__ float2 buf[1024];
    __shared__ float2 W[1024];
    int row = blockIdx.x, z = blockIdx.y, tid = threadIdx.x;
    fill_W(W, tid, 256);
    float zf = defocus[z];
    float y  = (float)(-1.8 + row*(3.6/1023.0));
    const float KF = (float)KD;
    const float2* pha = phiA + ((size_t)row << 10);
    for (int k = 0; k < 4; ++k){
        int c = tid + k*256;
        float x = (float)(-1.8 + c*(3.6/1023.0));
        float2 pa = pha[c];
        float2 u  = make_float2(0.f, 0.f);
        if (pa.y != 0.f){
            float q      = x*x + y*y;
            float phi_in = (KF*q) / (2.0f*zf);
            u = expi_from_double((double)(phi_in + pa.x));
        }
        buf[SW(c)] = u;
    }
    __syncthreads();
    fft1024_lds<false,256>(buf, W, tid);
    float2* Srow = S + ((size_t)z << 20) + ((size_t)row << 10);
    for (int k = 0; k < 4; ++k){ int c = tid + k*256; Srow[c] = buf[SW(c)]; }
}

// ---- P2 (col): fwd col FFT, *H (regs), inv col FFT, in place ----
__global__ __launch_bounds__(256) void k_p2(float2* __restrict__ S, const float2* __restrict__ HT){
    __shared__ float2 buf[CPB*CSTR];
    __shared__ float2 W[1024];
    int tid = threadIdx.x, bx = blockIdx.x, zz = blockIdx.y;
    int cb = ((bx & 7) << 5) | (bx >> 3);
    int c0 = cb*CPB;
    fill_W(W, tid, 256);
    float2* Sz = S + ((size_t)zz << 20);
    for (int it = 0; it < 16; ++it){
        int rr = it*64 + (tid>>2), cc = tid & 3;
        buf[cc*CSTR + SW(rr)] = Sz[((size_t)rr << 10) + c0 + cc];
    }
    __syncthreads();
    int col = tid >> 6, t = tid & 63;
    float2* B = buf + col*CSTR;
    float2 a[4][4], z[4][4];
    // forward
    r16_load(B, t, a); r16_s14<false>(a, W, z);
    __syncthreads(); r16_st1(B, t, z); __syncthreads();
    r16_load(B, t, a); r16_s16_64<false>(a, W, t, z);
    __syncthreads(); r16_st2(B, t, z); __syncthreads();
    r16_load(B, t, a); r16_s256<false>(a, W, t, z);
    // H in registers
    const float2* Hc = HT + ((size_t)(c0+col) << 10);
    #pragma unroll
    for (int k = 0; k < 4; ++k)
        #pragma unroll
        for (int d = 0; d < 4; ++d)
            z[k][d] = cmulf(z[k][d], Hc[t + 64*k + 256*d]);
    // inverse (pass 1 feeds directly from regs)
    r16_s14<true>(z, W, a);
    __syncthreads(); r16_st1(B, t, a); __syncthreads();
    r16_load(B, t, a); r16_s16_64<true>(a, W, t, z);
    __syncthreads(); r16_st2(B, t, z); __syncthreads();
    r16_load(B, t, a); r16_s256<true>(a, W, t, z);
    const float sc = 1.0f/1024.0f;
    #pragma unroll
    for (int k = 0; k < 4; ++k)
        #pragma unroll
        for (int d = 0; d < 4; ++d){ z[k][d].x *= sc; z[k][d].y *= sc; }
    __syncthreads();
    r16_st3(B, t, z);
    __syncthreads();
    for (int it = 0; it < 16; ++it){
        int rr = it*64 + (tid>>2), cc = tid & 3;
        Sz[((size_t)rr << 10) + c0 + cc] = buf[cc*CSTR + SW(rr)];
    }
}

// ---- P3 (row): inv row FFT -> p=|u|^2, partial sum(p), fwd row FFT of p ----
__global__ __launch_bounds__(256) void k_p3(float2* __restrict__ S, float* __restrict__ sumPart){
    __shared__ float2 buf[1024];
    __shared__ float2 W[1024];
    __shared__ float red[4];
    int row = blockIdx.x, z = blockIdx.y, tid = threadIdx.x;
    fill_W(W, tid, 256);
    float2* Srow = S + ((size_t)z << 20) + ((size_t)row << 10);
    for (int k = 0; k < 4; ++k){ int c = tid + k*256; buf[SW(c)] = Srow[c]; }
    __syncthreads();
    fft1024_lds<true,256>(buf, W, tid);
    const float s2 = (1.0f/1024.0f)*(1.0f/1024.0f);
    float pv[4]; float lsum = 0.f;
    for (int k = 0; k < 4; ++k){
        int c = tid + k*256;
        float2 u = buf[SW(c)];
        float p  = (u.x*u.x + u.y*u.y) * s2;
        pv[k] = p; lsum += p;
    }
    for (int k = 0; k < 4; ++k){ int c = tid + k*256; buf[SW(c)] = make_float2(pv[k], 0.f); }
    for (int o = 32; o > 0; o >>= 1) lsum += __shfl_down(lsum, o, 64);
    if ((tid & 63) == 0) red[tid >> 6] = lsum;
    __syncthreads();
    if (tid == 0) sumPart[z*1024 + row] = red[0]+red[1]+red[2]+red[3];
    fft1024_lds<false,256>(buf, W, tid);
    for (int k = 0; k < 4; ++k){ int c = tid + k*256; Srow[c] = buf[SW(c)]; }
}

// ---- R1: reduce sum(p) partials ----
__global__ __launch_bounds__(256) void k_r1(const float* __restrict__ sumPart, double* __restrict__ sums){
    __shared__ double dred[4];
    int z = blockIdx.x, tid = threadIdx.x;
    double s = 0.0;
    for (int i = tid; i < 1024; i += 256) s += (double)sumPart[z*1024 + i];
    for (int o = 32; o > 0; o >>= 1) s += __shfl_down(s, o, 64);
    if ((tid & 63) == 0) dred[tid >> 6] = s;
    __syncthreads();
    if (tid == 0) sums[z] = dred[0]+dred[1]+dred[2]+dred[3];
}

// ---- P4 (col): fwd col FFT, scale 1/sum, masked diag partials (TM coalesced) ----
__global__ __launch_bounds__(256) void k_p4(float2* __restrict__ S, const double* __restrict__ sums,
        const float2* __restrict__ TM, float* __restrict__ dpart){
    __shared__ float2 buf[CPB*CSTR];
    __shared__ float2 W[1024];
    __shared__ float red[4];
    int tid = threadIdx.x, bx = blockIdx.x, zz = blockIdx.y;
    int cb = ((bx & 7) << 5) | (bx >> 3);
    int c0 = cb*CPB;
    fill_W(W, tid, 256);
    float2* Sz = S + ((size_t)zz << 20);
    for (int it = 0; it < 16; ++it){
        int rr = it*64 + (tid>>2), cc = tid & 3;
        buf[cc*CSTR + SW(rr)] = Sz[((size_t)rr << 10) + c0 + cc];
    }
    __syncthreads();
    int col = tid >> 6, t = tid & 63;
    float2* B = buf + col*CSTR;
    float2 z[4][4];
    r16_fft<false>(B, W, t, z);
    float inv = (float)(1.0/sums[zz]);
    const float2* TMc = TM + ((size_t)(c0+col) << 10);
    const float nrm = 1.0f/1048576.0f;
    float dacc = 0.f;
    #pragma unroll
    for (int k = 0; k < 4; ++k)
        #pragma unroll
        for (int d = 0; d < 4; ++d){
            float2 s = z[k][d]; s.x *= inv; s.y *= inv; z[k][d] = s;
            float2 tm = TMc[t + 64*k + 256*d];
            float dff = (s.x*s.x + s.y*s.y - tm.x) * nrm;
            dacc += tm.y * dff * dff;
        }
    __syncthreads();
    r16_st3(B, t, z);
    __syncthreads();
    for (int it = 0; it < 16; ++it){
        int rr = it*64 + (tid>>2), cc = tid & 3;
        Sz[((size_t)rr << 10) + c0 + cc] = buf[cc*CSTR + SW(rr)];
    }
    for (int o = 32; o > 0; o >>= 1) dacc += __shfl_down(dacc, o, 64);
    if ((tid & 63) == 0) red[tid >> 6] = dacc;
    __syncthreads();
    if (tid == 0) dpart[zz*256 + cb] = red[0]+red[1]+red[2]+red[3];
}

static __device__ __forceinline__ void pair_of(int p, int& a, int& b){
    int i = 0, c = NZ-1;
    while (p >= c){ p -= c; ++i; --c; }
    a = i; b = i + 1 + p;
}

// ---- pairA (row): Z = conj(Si1)Sj1 + i*conj(Si2)Sj2, inv row FFT -> U ----
__global__ __launch_bounds__(256) void k_pairA(const float2* __restrict__ S,
        float2* __restrict__ U, int ubase){
    __shared__ float2 buf[1024];
    __shared__ float2 W[1024];
    int row = blockIdx.x, ug = blockIdx.y, tid = threadIdx.x;
    int u = ubase + ug;
    int pa = 2*u, pb = (2*u+1 < NPAIR) ? (2*u+1) : (NPAIR-1);
    int i1, i2, j1, j2;
    pair_of(pa, i1, i2); pair_of(pb, j1, j2);
    const float2* A1 = S + ((size_t)i1 << 20) + ((size_t)row << 10);
    const float2* A2 = S + ((size_t)i2 << 20) + ((size_t)row << 10);
    const float2* B1 = S + ((size_t)j1 << 20) + ((size_t)row << 10);
    const float2* B2 = S + ((size_t)j2 << 20) + ((size_t)row << 10);
    fill_W(W, tid, 256);
    for (int k = 0; k < 4; ++k){
        int c = tid + k*256;
        float2 x1 = A1[c], y1 = A2[c], x2 = B1[c], y2 = B2[c];
        float2 g1 = make_float2(x1.x*y1.x + x1.y*y1.y, x1.x*y1.y - x1.y*y1.x);
        float2 g2 = make_float2(x2.x*y2.x + x2.y*y2.y, x2.x*y2.y - x2.y*y2.x);
        buf[SW(c)] = make_float2(g1.x - g2.y, g1.y + g2.x);
    }
    __syncthreads();
    fft1024_lds<true,256>(buf, W, tid);
    const float sc = 1.0f/1024.0f;
    float2* Up = U + ((size_t)ug << 20) + ((size_t)row << 10);
    for (int k = 0; k < 4; ++k){
        int c = tid + k*256;
        float2 v = buf[SW(c)];
        Up[c] = make_float2(v.x*sc, v.y*sc);
    }
}

// ---- pairB (col): inv col FFT, c1=|Re|,c2=|Im|, per-block lse partials ----
__global__ __launch_bounds__(256) void k_pairB(const float2* __restrict__ U,
        float2* __restrict__ lsePart, int ubase){
    __shared__ float2 buf[CPB*CSTR];
    __shared__ float2 W[1024];
    __shared__ float2 redA[4], redB[4];
    int tid = threadIdx.x, bx = blockIdx.x, ug = blockIdx.y;
    int cb = ((bx & 7) << 5) | (bx >> 3);
    int c0 = cb*CPB;
    int u = ubase + ug;
    fill_W(W, tid, 256);
    const float2* Up = U + ((size_t)ug << 20);
    for (int it = 0; it < 16; ++it){
        int rr = it*64 + (tid>>2), cc = tid & 3;
        buf[cc*CSTR + SW(rr)] = Up[((size_t)rr << 10) + c0 + cc];
    }
    __syncthreads();
    int col = tid >> 6, t = tid & 63;
    float2* B = buf + col*CSTR;
    float2 z[4][4];
    r16_fft<true>(B, W, t, z);
    const float sc = 1.0f/1024.0f;
    float m1 = -1.f, m2 = -1.f;
    #pragma unroll
    for (int k = 0; k < 4; ++k)
        #pragma unroll
        for (int d = 0; d < 4; ++d){
            float c1 = fabsf(z[k][d].x)*sc, c2 = fabsf(z[k][d].y)*sc;
            z[k][d] = make_float2(c1, c2);
            m1 = fmaxf(m1, c1); m2 = fmaxf(m2, c2);
        }
    for (int o = 32; o > 0; o >>= 1){
        m1 = fmaxf(m1, __shfl_down(m1, o, 64));
        m2 = fmaxf(m2, __shfl_down(m2, o, 64));
    }
    if ((tid & 63) == 0) redA[tid >> 6] = make_float2(m1, m2);
    __syncthreads();
    float M1 = fmaxf(fmaxf(redA[0].x, redA[1].x), fmaxf(redA[2].x, redA[3].x));
    float M2 = fmaxf(fmaxf(redA[0].y, redA[1].y), fmaxf(redA[2].y, redA[3].y));
    float s1 = 0.f, s2 = 0.f;
    #pragma unroll
    for (int k = 0; k < 4; ++k)
        #pragma unroll
        for (int d = 0; d < 4; ++d){
            s1 += expf((z[k][d].x - M1) * 100.0f);
            s2 += expf((z[k][d].y - M2) * 100.0f);
        }
    for (int o = 32; o > 0; o >>= 1){
        s1 += __shfl_down(s1, o, 64);
        s2 += __shfl_down(s2, o, 64);
    }
    if ((tid & 63) == 0) redB[tid >> 6] = make_float2(s1, s2);
    __syncthreads();
    if (tid == 0){
        lsePart[(size_t)(2*u)*256 + cb] = make_float2(M1, redB[0].x+redB[1].x+redB[2].x+redB[3].x);
        if (2*u+1 < NPAIR)
            lsePart[(size_t)(2*u+1)*256 + cb] = make_float2(M2, redB[0].y+redB[1].y+redB[2].y+redB[3].y);
    }
}

// ---- final: 10 diag sums + 45 off ----
__global__ __launch_bounds__(256) void k_final(const float* __restrict__ dpart,
        const float2* __restrict__ lsePart, float* __restrict__ out){
    __shared__ double dred[4];
    __shared__ float fred[4];
    int b = blockIdx.x, tid = threadIdx.x;
    if (b < NZ){
        double s = (double)dpart[b*256 + tid];
        for (int o = 32; o > 0; o >>= 1) s += __shfl_down(s, o, 64);
        if ((tid & 63) == 0) dred[tid >> 6] = s;
        __syncthreads();
        if (tid == 0) out[b] = (float)(dred[0]+dred[1]+dred[2]+dred[3]);
    } else {
        int p = b - NZ;
        float2 v = lsePart[(size_t)p*256 + tid];
        float m = v.x;
        for (int o = 32; o > 0; o >>= 1) m = fmaxf(m, __shfl_down(m, o, 64));
        if ((tid & 63) == 0) fred[tid >> 6] = m;
        __syncthreads();
        float M = fmaxf(fmaxf(fred[0], fred[1]), fmaxf(fred[2], fred[3]));
        double s = (double)v.y * (double)expf((v.x - M)*100.0f);
        for (int o = 32; o > 0; o >>= 1) s += __shfl_down(s, o, 64);
        if ((tid & 63) == 0) dred[tid >> 6] = s;
        __syncthreads();
        if (tid == 0)
            out[NZ + p] = (float)(30.0*(double)M + 0.3*log(dred[0]+dred[1]+dred[2]+dred[3]));
    }
}

extern "C" void kernel_launch(void* const* d_in, const int* in_sizes, int n_in,
                              void* d_out, int out_size, void* d_ws, size_t ws_size,
                              hipStream_t stream){
    const float* rlist   = (const float*)d_in[0];
    const float* xpos    = (const float*)d_in[1];
    const float* ypos    = (const float*)d_in[2];
    const float* defocus = (const float*)d_in[3];
    const float* tF      = (const float*)d_in[4];
    const float* dmask   = (const float*)d_in[5];
    float* out = (float*)d_out;

    char* ws = (char*)d_ws;
    float2* S       = (float2*)(ws);                         // 80 MiB
    char*   X       = ws + 83886080;                         // 40 MiB region
    float2* phiA    = (float2*)(X);                          // 8 MiB (dead after p1)
    float2* HT      = (float2*)(X + 8388608);                // 8 MiB (dead after p2)
    float2* TM      = (float2*)(X + 16777216);               // 8 MiB (dead after p4)
    float2* U       = (float2*)(X);                          // 32 MiB (alive from pairA on)
    char*   tail    = ws + 125829120;
    float*  sumPart = (float*) (tail);                       // 40 KiB
    double* sums    = (double*)(tail + 65536);               // 80 B
    float*  dpart   = (float*) (tail + 66560);               // 10 KiB
    float2* lsePart = (float2*)(tail + 81920);               // 90 KiB

    k_lens   <<<4096, 256, 0, stream>>>(rlist, xpos, ypos, phiA);
    k_prep_h <<<4096, 256, 0, stream>>>(HT);
    k_prep_tm<<<dim3(32,32), dim3(32,8), 0, stream>>>(tF, dmask, TM);
    k_p1 <<<dim3(1024, NZ), 256, 0, stream>>>(phiA, defocus, S);
    k_p2 <<<dim3(256,  NZ), 256, 0, stream>>>(S, HT);
    k_p3 <<<dim3(1024, NZ), 256, 0, stream>>>(S, sumPart);
    k_r1 <<<NZ, 256, 0, stream>>>(sumPart, sums);
    k_p4 <<<dim3(256,  NZ), 256, 0, stream>>>(S, sums, TM, dpart);
    for (int g = 0; g < NUNIT; g += UBATCH){
        int cnt = (NUNIT - g < UBATCH) ? (NUNIT - g) : UBATCH;
        k_pairA<<<dim3(1024, cnt), 256, 0, stream>>>(S, U, g);
        k_pairB<<<dim3(256,  cnt), 256, 0, stream>>>(U, lsePart, g);
    }
    k_final<<<NZ + NPAIR, 256, 0, stream>>>(dpart, lsePart, out);
}